// Round 13
// baseline (327.740 us; speedup 1.0000x reference)
//
#include <hip/hip_runtime.h>

#define NN 50000
#define HALF 25000
#define NV (2 * NN)
#define NE 800000

typedef __attribute__((ext_vector_type(8))) short bf16x8;
typedef __attribute__((ext_vector_type(4))) float f32x4;
typedef __attribute__((ext_vector_type(2))) float f32x2;

__device__ inline short f2bf(float f) {
    union { float f; unsigned u; } v; v.f = f;
    unsigned r = v.u + 0x7fffu + ((v.u >> 16) & 1u);
    return (short)(r >> 16);
}
__device__ inline float bf2f(short s) {
    union { unsigned u; float f; } v;
    v.u = ((unsigned)(unsigned short)s) << 16;
    return v.f;
}

// ---------------- bucketed CSR build (2 buckets by src half, dst-grouped within) ----
__global__ __launch_bounds__(256) void count_deg_kernel(const int* __restrict__ src,
                                                        const int* __restrict__ dst,
                                                        int* __restrict__ deg2, int n) {
    int e = blockIdx.x * 256 + threadIdx.x;
    if (e < n) {
        int b = (src[e] < HALF) ? 0 : 1;
        atomicAdd(&deg2[b * NN + dst[e]], 1);
    }
}

__global__ __launch_bounds__(512) void scan1_kernel(const int* __restrict__ deg,
                                                    int* __restrict__ off,
                                                    int* __restrict__ bsum, int n) {
    __shared__ int s[512];
    int t = threadIdx.x;
    int i = blockIdx.x * 512 + t;
    int v = (i < n) ? deg[i] : 0;
    s[t] = v;
    __syncthreads();
    for (int d = 1; d < 512; d <<= 1) {
        int u = (t >= d) ? s[t - d] : 0;
        __syncthreads();
        s[t] += u;
        __syncthreads();
    }
    if (i < n) off[i] = s[t] - v;
    if (t == 511) bsum[blockIdx.x] = s[511];
}

// merged: block-prefix of bsum + global off/cursor + edst fill (cursor aliases deg2)
__global__ __launch_bounds__(512) void scan3x_kernel(
    int* __restrict__ off, const int* __restrict__ bsum,
    int* __restrict__ cursor, unsigned short* __restrict__ edst,
    int n, int total, int nb) {
    __shared__ int s[512];
    int t = threadIdx.x;
    int v = (t < nb) ? bsum[t] : 0;
    s[t] = v;
    __syncthreads();
    for (int d = 1; d < 512; d <<= 1) {
        int u = (t >= d) ? s[t - d] : 0;
        __syncthreads();
        s[t] += u;
        __syncthreads();
    }
    int base = (blockIdx.x == 0) ? 0 : s[blockIdx.x - 1];
    int i = blockIdx.x * 512 + t;
    if (i < n) {
        int d = cursor[i];                 // deg (aliased)
        int v2 = off[i] + base;
        off[i] = v2;
        cursor[i] = v2;
        int node = (i >= NN) ? (i - NN) : i;
        for (int p = v2; p < v2 + d; ++p) edst[p] = (unsigned short)node;
    }
    if (i == 0) off[n] = total;
}

__global__ __launch_bounds__(256) void fill_kernel(const int* __restrict__ src,
                                                   const int* __restrict__ dst,
                                                   int* __restrict__ cursor,
                                                   int* __restrict__ col,
                                                   int* __restrict__ pos, int n) {
    int e = blockIdx.x * 256 + threadIdx.x;
    if (e < n) {
        int sv = src[e];
        int b = (sv < HALF) ? 0 : 1;
        int p = atomicAdd(&cursor[b * NN + dst[e]], 1);
        col[p] = sv;
        pos[e] = p;
    }
}

// ---------------- pack one f32 KxN matrix into bf16 MFMA B-fragments --------------
__device__ inline void pack_one(const float* B, int K, int N, short* out, int t) {
    int l = t & 63;
    int fs = t >> 6;
    int KS = K >> 5;
    int ct = fs / KS, ks = fs - ct * KS;
    int coln = ct * 16 + (l & 15);
    int k0 = ks * 32 + (l >> 4) * 8;
    bf16x8 v;
#pragma unroll
    for (int j = 0; j < 8; ++j)
        v[j] = f2bf(B[(size_t)(k0 + j) * N + coln]);
    *(bf16x8*)(out + (size_t)t * 8) = v;
}

__global__ __launch_bounds__(256) void pack_all_kernel(
    const float* __restrict__ Wl0, const float* __restrict__ Wr0,
    const float* __restrict__ Wl1, const float* __restrict__ Wr1,
    const float* __restrict__ Wl2, const float* __restrict__ Wr2,
    const float* __restrict__ Wf1,
    short* W0lp, short* W0rp, short* W1lp, short* W1rp,
    short* W2lp, short* W2rp, short* Wfp) {
    int t = blockIdx.x * 256 + threadIdx.x;
    if (t < 2048)              pack_one(Wl0, 128, 128, W0lp, t);
    else if (t < 4096)         pack_one(Wr0, 128, 128, W0rp, t - 2048);
    else if (t < 6144)         pack_one(Wl1, 128, 128, W1lp, t - 4096);
    else if (t < 8192)         pack_one(Wr1, 128, 128, W1rp, t - 6144);
    else if (t < 9216)         pack_one(Wl2, 128, 64,  W2lp, t - 8192);
    else if (t < 10240)        pack_one(Wr2, 128, 64,  W2rp, t - 9216);
    else if (t < 12288)        pack_one(Wf1, 128, 128, Wfp,  t - 10240);
}

// ---------------- transform GEMM: g = h@Wl ; r = h@Wr + b  (K=128) ----------------
template <int NT, bool SRC_F32, bool G_FP8>
__global__ __launch_bounds__(256) void gemm_tf_kernel(
    const void* hsrc, const short* __restrict__ Wlp, const short* __restrict__ Wrp,
    const float* __restrict__ b, void* g, short* r, int n) {
    int wave = (blockIdx.x * 256 + threadIdx.x) >> 6;
    int lane = threadIdx.x & 63;
    int rowbase = wave * 32;
    if (rowbase >= n) return;
    int gq = lane >> 4, c = lane & 15;

    bf16x8 afrag[2][4];
#pragma unroll
    for (int s = 0; s < 2; ++s) {
        int i = rowbase + s * 16 + c;
        if (i >= n) i = n - 1;
        if (SRC_F32) {
            const float* xr = (const float*)hsrc + (size_t)i * 128;
#pragma unroll
            for (int ks = 0; ks < 4; ++ks) {
                const float* p = xr + ks * 32 + gq * 8;
                float4 v0 = *(const float4*)p;
                float4 v1 = *(const float4*)(p + 4);
                bf16x8 a;
                a[0] = f2bf(v0.x); a[1] = f2bf(v0.y); a[2] = f2bf(v0.z); a[3] = f2bf(v0.w);
                a[4] = f2bf(v1.x); a[5] = f2bf(v1.y); a[6] = f2bf(v1.z); a[7] = f2bf(v1.w);
                afrag[s][ks] = a;
            }
        } else {
            const short* hr = (const short*)hsrc + (size_t)i * 128;
#pragma unroll
            for (int ks = 0; ks < 4; ++ks)
                afrag[s][ks] = *(const bf16x8*)(hr + ks * 32 + gq * 8);
        }
    }

    f32x4 acc[2][NT];
    f32x4 z = {0.f, 0.f, 0.f, 0.f};
    const int NG = NT * 16;

    // ---- phase 1: g = h @ Wl ----
#pragma unroll
    for (int s = 0; s < 2; ++s)
#pragma unroll
        for (int ct = 0; ct < NT; ++ct) acc[s][ct] = z;
#pragma unroll
    for (int ct = 0; ct < NT; ++ct)
#pragma unroll
        for (int ks = 0; ks < 4; ++ks) {
            bf16x8 bfv = *(const bf16x8*)(Wlp + ((size_t)(ct * 4 + ks) * 64 + lane) * 8);
            acc[0][ct] = __builtin_amdgcn_mfma_f32_16x16x32_bf16(afrag[0][ks], bfv, acc[0][ct], 0, 0, 0);
            acc[1][ct] = __builtin_amdgcn_mfma_f32_16x16x32_bf16(afrag[1][ks], bfv, acc[1][ct], 0, 0, 0);
        }
#pragma unroll
    for (int s = 0; s < 2; ++s)
#pragma unroll
        for (int ct = 0; ct < NT; ++ct)
#pragma unroll
            for (int rr = 0; rr < 4; ++rr) {
                int row = rowbase + s * 16 + gq * 4 + rr;
                if (row < n) {
                    float v = acc[s][ct][rr];
                    if (G_FP8) {
                        unsigned pk = __builtin_amdgcn_cvt_pk_fp8_f32(v, v, 0u, false);
                        ((unsigned char*)g)[(size_t)row * NG + ct * 16 + c] = (unsigned char)pk;
                    } else {
                        ((short*)g)[(size_t)row * NG + ct * 16 + c] = f2bf(v);
                    }
                }
            }

    // ---- phase 2: r = h @ Wr + b ----
#pragma unroll
    for (int s = 0; s < 2; ++s)
#pragma unroll
        for (int ct = 0; ct < NT; ++ct) acc[s][ct] = z;
#pragma unroll
    for (int ct = 0; ct < NT; ++ct)
#pragma unroll
        for (int ks = 0; ks < 4; ++ks) {
            bf16x8 bfv = *(const bf16x8*)(Wrp + ((size_t)(ct * 4 + ks) * 64 + lane) * 8);
            acc[0][ct] = __builtin_amdgcn_mfma_f32_16x16x32_bf16(afrag[0][ks], bfv, acc[0][ct], 0, 0, 0);
            acc[1][ct] = __builtin_amdgcn_mfma_f32_16x16x32_bf16(afrag[1][ks], bfv, acc[1][ct], 0, 0, 0);
        }
#pragma unroll
    for (int s = 0; s < 2; ++s)
#pragma unroll
        for (int ct = 0; ct < NT; ++ct)
#pragma unroll
            for (int rr = 0; rr < 4; ++rr) {
                int row = rowbase + s * 16 + gq * 4 + rr;
                if (row < n)
                    r[(size_t)row * 128 + ct * 16 + c] = f2bf(acc[s][ct][rr] + b[ct * 16 + c]);
            }
}

// ---------------- combine (fp8 g): h' = relu(mean_gather(g8) + r) ----------------
__device__ inline void acc_fp8x16(unsigned x, unsigned y, unsigned z, unsigned w, float* a) {
    f32x2 d;
    d = __builtin_amdgcn_cvt_pk_f32_fp8((int)x, false); a[0] += d.x;  a[1] += d.y;
    d = __builtin_amdgcn_cvt_pk_f32_fp8((int)x, true);  a[2] += d.x;  a[3] += d.y;
    d = __builtin_amdgcn_cvt_pk_f32_fp8((int)y, false); a[4] += d.x;  a[5] += d.y;
    d = __builtin_amdgcn_cvt_pk_f32_fp8((int)y, true);  a[6] += d.x;  a[7] += d.y;
    d = __builtin_amdgcn_cvt_pk_f32_fp8((int)z, false); a[8] += d.x;  a[9] += d.y;
    d = __builtin_amdgcn_cvt_pk_f32_fp8((int)z, true);  a[10] += d.x; a[11] += d.y;
    d = __builtin_amdgcn_cvt_pk_f32_fp8((int)w, false); a[12] += d.x; a[13] += d.y;
    d = __builtin_amdgcn_cvt_pk_f32_fp8((int)w, true);  a[14] += d.x; a[15] += d.y;
}

__device__ inline void gather_fp8_range(const unsigned char* __restrict__ g8,
                                        const int* __restrict__ col,
                                        int p0, int p1, int qo, float* a) {
    int p = p0;
    for (; p + 3 < p1; p += 4) {
        int c0 = __builtin_nontemporal_load(col + p);
        int c1 = __builtin_nontemporal_load(col + p + 1);
        int c2 = __builtin_nontemporal_load(col + p + 2);
        int c3 = __builtin_nontemporal_load(col + p + 3);
        uint4 u0 = *(const uint4*)(g8 + (size_t)c0 * 128 + qo);
        uint4 u1 = *(const uint4*)(g8 + (size_t)c1 * 128 + qo);
        uint4 u2 = *(const uint4*)(g8 + (size_t)c2 * 128 + qo);
        uint4 u3 = *(const uint4*)(g8 + (size_t)c3 * 128 + qo);
        acc_fp8x16(u0.x, u0.y, u0.z, u0.w, a);
        acc_fp8x16(u1.x, u1.y, u1.z, u1.w, a);
        acc_fp8x16(u2.x, u2.y, u2.z, u2.w, a);
        acc_fp8x16(u3.x, u3.y, u3.z, u3.w, a);
    }
    for (; p < p1; ++p) {
        int c0 = __builtin_nontemporal_load(col + p);
        uint4 u = *(const uint4*)(g8 + (size_t)c0 * 128 + qo);
        acc_fp8x16(u.x, u.y, u.z, u.w, a);
    }
}

__global__ __launch_bounds__(256) void combine_fp8_kernel(
    const unsigned char* __restrict__ g8, const short* rr,
    const int* __restrict__ off2, const int* __restrict__ col,
    short* outb, int n) {
    int t = blockIdx.x * 256 + threadIdx.x;
    int node = t >> 3, q = t & 7;
    if (node >= n) return;
    int qo = q * 16;
    float a[16];
#pragma unroll
    for (int k = 0; k < 16; ++k) a[k] = 0.f;
    int p0a = off2[node],      p1a = off2[node + 1];
    int p0b = off2[NN + node], p1b = off2[NN + node + 1];
    gather_fp8_range(g8, col, p0a, p1a, qo, a);    // rows in [0, HALF): 3.2 MB
    gather_fp8_range(g8, col, p0b, p1b, qo, a);    // rows in [HALF, NN): 3.2 MB
    int deg = (p1a - p0a) + (p1b - p0b);
    float inv = 1.f / (float)(deg > 1 ? deg : 1);
    const short* rrow = rr + (size_t)node * 128 + q * 16;
    bf16x8 rv0 = __builtin_nontemporal_load((const bf16x8*)rrow);
    bf16x8 rv1 = __builtin_nontemporal_load((const bf16x8*)(rrow + 8));
    bf16x8 o0, o1;
#pragma unroll
    for (int k = 0; k < 8; ++k) {
        o0[k] = f2bf(fmaxf(a[k] * inv + bf2f(rv0[k]), 0.f));
        o1[k] = f2bf(fmaxf(a[k + 8] * inv + bf2f(rv1[k]), 0.f));
    }
    short* orow = outb + (size_t)node * 128 + q * 16;
    *(bf16x8*)orow = o0;
    *(bf16x8*)(orow + 8) = o1;
}

// ------- combine layer 2 + fused classifier ----------------------------------------
__device__ inline void gather_bf16_range(const short* __restrict__ g,
                                         const int* __restrict__ col,
                                         int p0, int p1, int qo, float* a) {
    int p = p0;
    for (; p + 3 < p1; p += 4) {
        int c0 = __builtin_nontemporal_load(col + p);
        int c1 = __builtin_nontemporal_load(col + p + 1);
        int c2 = __builtin_nontemporal_load(col + p + 2);
        int c3 = __builtin_nontemporal_load(col + p + 3);
        bf16x8 u0 = *(const bf16x8*)(g + (size_t)c0 * 64 + qo);
        bf16x8 u1 = *(const bf16x8*)(g + (size_t)c1 * 64 + qo);
        bf16x8 u2 = *(const bf16x8*)(g + (size_t)c2 * 64 + qo);
        bf16x8 u3 = *(const bf16x8*)(g + (size_t)c3 * 64 + qo);
#pragma unroll
        for (int k = 0; k < 8; ++k)
            a[k] += (bf2f(u0[k]) + bf2f(u1[k])) + (bf2f(u2[k]) + bf2f(u3[k]));
    }
    for (; p < p1; ++p) {
        int c0 = __builtin_nontemporal_load(col + p);
        bf16x8 u0 = *(const bf16x8*)(g + (size_t)c0 * 64 + qo);
#pragma unroll
        for (int k = 0; k < 8; ++k) a[k] += bf2f(u0[k]);
    }
}

__global__ __launch_bounds__(256) void combine_l2_kernel(
    const short* __restrict__ g, const short* rr,
    const int* __restrict__ off2, const int* __restrict__ col,
    short* neb, float* nef, const float* __restrict__ Wc,
    const float* __restrict__ bc, float* __restrict__ sc, int n) {
    int t = blockIdx.x * 256 + threadIdx.x;
    int node = t >> 3, q = t & 7;
    if (node >= n) return;
    int qo = q * 8;
    float a[8];
#pragma unroll
    for (int k = 0; k < 8; ++k) a[k] = 0.f;
    int p0a = off2[node],      p1a = off2[node + 1];
    int p0b = off2[NN + node], p1b = off2[NN + node + 1];
    gather_bf16_range(g, col, p0a, p1a, qo, a);
    gather_bf16_range(g, col, p0b, p1b, qo, a);
    int deg = (p1a - p0a) + (p1b - p0b);
    float inv = 1.f / (float)(deg > 1 ? deg : 1);
    bf16x8 rv = __builtin_nontemporal_load((const bf16x8*)(rr + (size_t)node * 128 + qo));
    float val[8];
#pragma unroll
    for (int k = 0; k < 8; ++k) val[k] = a[k] * inv + bf2f(rv[k]);
    float4 f0, f1;
    f0.x = val[0]; f0.y = val[1]; f0.z = val[2]; f0.w = val[3];
    f1.x = val[4]; f1.y = val[5]; f1.z = val[6]; f1.w = val[7];
    *(float4*)(nef + (size_t)node * 64 + qo) = f0;
    *(float4*)(nef + (size_t)node * 64 + qo + 4) = f1;
    bf16x8 o;
#pragma unroll
    for (int k = 0; k < 8; ++k) o[k] = f2bf(val[k]);
    *(bf16x8*)(neb + (size_t)node * 64 + qo) = o;

    float part[4];
#pragma unroll
    for (int cidx = 0; cidx < 4; ++cidx) {
        float s0 = 0.f;
#pragma unroll
        for (int k = 0; k < 8; ++k)
            s0 = fmaf(val[k], Wc[(qo + k) * 4 + cidx], s0);
        s0 += __shfl_xor(s0, 1);
        s0 += __shfl_xor(s0, 2);
        s0 += __shfl_xor(s0, 4);
        part[cidx] = s0;
    }
    if (q == 0) {
        float4 o4;
        o4.x = part[0] + bc[0]; o4.y = part[1] + bc[1];
        o4.z = part[2] + bc[2]; o4.w = part[3] + bc[3];
        *(float4*)(sc + (size_t)node * 4) = o4;
    }
}

// ------- edge MLP phase A (bucketed dst-grouped order, coalesced position output) ---
__global__ __launch_bounds__(256) void edge_mlp_sorted_kernel(
    const short* __restrict__ neb, const int* __restrict__ col,
    const unsigned short* __restrict__ edst,
    const short* __restrict__ Wp, const float* __restrict__ bf1,
    const float* __restrict__ Wf2, const float* __restrict__ bf2,
    float* __restrict__ cfs, int nE) {
    int wave = (blockIdx.x * 256 + threadIdx.x) >> 6;
    int lane = threadIdx.x & 63;
    int rowbase = wave * 32;
    if (rowbase >= nE) return;
    int g = lane >> 4, c = lane & 15;

    bf16x8 afrag[2][4];
#pragma unroll
    for (int s = 0; s < 2; ++s) {
        int p = rowbase + s * 16 + c;
        int sv = __builtin_nontemporal_load(col + p);
        int dv = __builtin_nontemporal_load(edst + p);
        const short* rs = neb + (size_t)sv * 64;
        const short* rd = neb + (size_t)dv * 64;
        afrag[s][0] = *(const bf16x8*)(rs + g * 8);
        afrag[s][1] = *(const bf16x8*)(rs + 32 + g * 8);
        afrag[s][2] = *(const bf16x8*)(rd + g * 8);
        afrag[s][3] = *(const bf16x8*)(rd + 32 + g * 8);
    }

    f32x4 acc[2][8];
    f32x4 z = {0.f, 0.f, 0.f, 0.f};
#pragma unroll
    for (int s = 0; s < 2; ++s)
#pragma unroll
        for (int ct = 0; ct < 8; ++ct) acc[s][ct] = z;

#pragma unroll
    for (int ct = 0; ct < 8; ++ct)
#pragma unroll
        for (int ks = 0; ks < 4; ++ks) {
            bf16x8 bfv = *(const bf16x8*)(Wp + ((size_t)(ct * 4 + ks) * 64 + lane) * 8);
            acc[0][ct] = __builtin_amdgcn_mfma_f32_16x16x32_bf16(afrag[0][ks], bfv, acc[0][ct], 0, 0, 0);
            acc[1][ct] = __builtin_amdgcn_mfma_f32_16x16x32_bf16(afrag[1][ks], bfv, acc[1][ct], 0, 0, 0);
        }

    float bf1v[8], wf2v[8];
#pragma unroll
    for (int ct = 0; ct < 8; ++ct) {
        bf1v[ct] = bf1[ct * 16 + c];
        wf2v[ct] = Wf2[ct * 16 + c];
    }
    float bias2 = bf2[0];
#pragma unroll
    for (int s = 0; s < 2; ++s)
#pragma unroll
        for (int r = 0; r < 4; ++r) {
            float part = 0.f;
#pragma unroll
            for (int ct = 0; ct < 8; ++ct) {
                float hv = acc[s][ct][r] + bf1v[ct];
                hv = fmaxf(hv, 0.f);
                part = fmaf(hv, wf2v[ct], part);
            }
#pragma unroll
            for (int o = 1; o < 16; o <<= 1)
                part += __shfl_xor(part, o);
            if (c == 0) {
                int row = rowbase + s * 16 + g * 4 + r;
                cfs[row] = part + bias2;
            }
        }
}

// phase B: cf[e] = cfs[pos[e]] (cfs stays L2-resident via normal stores)
__global__ __launch_bounds__(256) void permute_kernel(const float* __restrict__ cfs,
                                                      const int* __restrict__ pos,
                                                      float* __restrict__ cf, int n) {
    int e = blockIdx.x * 256 + threadIdx.x;
    if (e < n) {
        int p = __builtin_nontemporal_load(pos + e);
        cf[e] = cfs[p];
    }
}

extern "C" void kernel_launch(void* const* d_in, const int* in_sizes, int n_in,
                              void* d_out, int out_size, void* d_ws, size_t ws_size,
                              hipStream_t stream) {
    const float* x   = (const float*)d_in[0];
    const int*   ei  = (const int*)d_in[1];
    const int*   src = ei;
    const int*   dst = ei + NE;
    const float* Wl0 = (const float*)d_in[2];
    const float* Wr0 = (const float*)d_in[3];
    const float* b0  = (const float*)d_in[4];
    const float* Wl1 = (const float*)d_in[5];
    const float* Wr1 = (const float*)d_in[6];
    const float* b1  = (const float*)d_in[7];
    const float* Wl2 = (const float*)d_in[8];
    const float* Wr2 = (const float*)d_in[9];
    const float* b2  = (const float*)d_in[10];
    const float* Wf1 = (const float*)d_in[11];
    const float* bf1 = (const float*)d_in[12];
    const float* Wf2 = (const float*)d_in[13];
    const float* bf2 = (const float*)d_in[14];
    const float* Wc  = (const float*)d_in[15];
    const float* bc  = (const float*)d_in[16];

    // ---- workspace carve-up (~34.7 MB; ws_size >= 37.75 MB proven in R5/R9/R10) ----
    short* sp = (short*)d_ws;
    short* W0lp = sp; sp += 128 * 128;
    short* W0rp = sp; sp += 128 * 128;
    short* W1lp = sp; sp += 128 * 128;
    short* W1rp = sp; sp += 128 * 128;
    short* W2lp = sp; sp += 128 * 64;
    short* W2rp = sp; sp += 128 * 64;
    short* Wfp  = sp; sp += 128 * 128;
    short* gb   = sp; sp += (size_t)NN * 64;    // 6.4 MB: fp8 g[NN,128]B | bf16 g2[NN,64] | cfs
    short* hb   = sp; sp += (size_t)NN * 128;   // 12.8 MB: r/h rows (in place)
    short* neb  = sp; sp += (size_t)NN * 64;    // 6.4 MB: compact bf16 node embeddings
    int* ip = (int*)sp;
    int* off2    = ip; ip += NV + 4;            // bucketed CSR offsets (2*NN+1)
    int* cursor2 = ip; ip += NV;                // also deg2
    int* col     = ip; ip += NE;
    int* bsum    = ip; ip += 512;
    int* pos     = ip; ip += NE;
    unsigned short* edst = (unsigned short*)ip;

    float* cfs = (float*)gb;                    // aliases gb (free after combine_l2)

    float* ne = (float*)d_out;               // [NN,64]
    float* cf = ne + (size_t)NN * 64;        // [NE]
    float* sc = cf + NE;                     // [NN,4]

    int* deg2 = cursor2;
    const int NB5 = (NV + 511) / 512;        // 196

    // --- bucketed CSR build ---
    hipMemsetAsync(deg2, 0, NV * sizeof(int), stream);
    count_deg_kernel<<<(NE + 255) / 256, 256, 0, stream>>>(src, dst, deg2, NE);
    scan1_kernel<<<NB5, 512, 0, stream>>>(deg2, off2, bsum, NV);
    scan3x_kernel<<<NB5, 512, 0, stream>>>(off2, bsum, cursor2, edst, NV, NE, NB5);
    fill_kernel<<<(NE + 255) / 256, 256, 0, stream>>>(src, dst, cursor2, col, pos, NE);

    // --- weight packs ---
    pack_all_kernel<<<48, 256, 0, stream>>>(Wl0, Wr0, Wl1, Wr1, Wl2, Wr2, Wf1,
                                            W0lp, W0rp, W1lp, W1rp, W2lp, W2rp, Wfp);

    int sgrid  = ((NN + 31) / 32 + 3) / 4;       // 391
    int cgrid  = (NN * 8 + 255) / 256;           // 1563 (8 lanes/node)
    int egrid  = (NE / 32) / 4;                  // 6250

    // --- layer 0: A from f32 x; g0 fp8 -> gb; r0 -> hb; combine -> hb ---
    gemm_tf_kernel<8, true, true><<<sgrid, 256, 0, stream>>>(x, W0lp, W0rp, b0, gb, hb, NN);
    combine_fp8_kernel<<<cgrid, 256, 0, stream>>>((const unsigned char*)gb, hb, off2, col, hb, NN);
    // --- layer 1 ---
    gemm_tf_kernel<8, false, true><<<sgrid, 256, 0, stream>>>(hb, W1lp, W1rp, b1, gb, hb, NN);
    combine_fp8_kernel<<<cgrid, 256, 0, stream>>>((const unsigned char*)gb, hb, off2, col, hb, NN);
    // --- layer 2: g2 bf16 64-wide -> gb; r2 -> hb; combine -> ne + neb + sc (fused) ---
    gemm_tf_kernel<4, false, false><<<sgrid, 256, 0, stream>>>(hb, W2lp, W2rp, b2, gb, hb, NN);
    combine_l2_kernel<<<cgrid, 256, 0, stream>>>(gb, hb, off2, col, neb, ne, Wc, bc, sc, NN);

    // --- edge head (bucketed position order -> src rows L2-resident per half) ---
    edge_mlp_sorted_kernel<<<egrid, 256, 0, stream>>>(neb, col, edst, Wfp, bf1, Wf2, bf2, cfs, NE);
    permute_kernel<<<(NE + 255) / 256, 256, 0, stream>>>(cfs, pos, cf, NE);
}

// Round 15
// 309.432 us; speedup vs baseline: 1.0592x; 1.0592x over previous
//
#include <hip/hip_runtime.h>

#define NN 50000
#define NE 800000

typedef __attribute__((ext_vector_type(8))) short bf16x8;
typedef __attribute__((ext_vector_type(4))) float f32x4;
typedef __attribute__((ext_vector_type(2))) float f32x2;

__device__ inline short f2bf(float f) {
    union { float f; unsigned u; } v; v.f = f;
    unsigned r = v.u + 0x7fffu + ((v.u >> 16) & 1u);
    return (short)(r >> 16);
}
__device__ inline float bf2f(short s) {
    union { unsigned u; float f; } v;
    v.u = ((unsigned)(unsigned short)s) << 16;
    return v.f;
}

// ---------------- CSR build ----------------
__global__ __launch_bounds__(256) void count_deg_kernel(const int* __restrict__ dst,
                                                        int* __restrict__ deg, int n) {
    int e = blockIdx.x * 256 + threadIdx.x;
    if (e < n) atomicAdd(&deg[dst[e]], 1);
}

__global__ __launch_bounds__(256) void scan1_kernel(const int* __restrict__ deg,
                                                    int* __restrict__ off,
                                                    int* __restrict__ bsum, int n) {
    __shared__ int s[256];
    int t = threadIdx.x;
    int i = blockIdx.x * 256 + t;
    int v = (i < n) ? deg[i] : 0;
    s[t] = v;
    __syncthreads();
    for (int d = 1; d < 256; d <<= 1) {
        int u = (t >= d) ? s[t - d] : 0;
        __syncthreads();
        s[t] += u;
        __syncthreads();
    }
    if (i < n) off[i] = s[t] - v;
    if (t == 255) bsum[blockIdx.x] = s[255];
}

// merged: block-prefix of bsum + global off/cursor + edst fill
// cursor aliases deg (deg read before overwrite, same thread)
__global__ __launch_bounds__(256) void scan3x_kernel(
    int* __restrict__ off, const int* __restrict__ bsum,
    int* __restrict__ cursor, unsigned short* __restrict__ edst,
    int n, int total, int nb) {
    __shared__ int s[256];
    int t = threadIdx.x;
    int v = (t < nb) ? bsum[t] : 0;
    s[t] = v;
    __syncthreads();
    for (int d = 1; d < 256; d <<= 1) {
        int u = (t >= d) ? s[t - d] : 0;
        __syncthreads();
        s[t] += u;
        __syncthreads();
    }
    int base = (blockIdx.x == 0) ? 0 : s[blockIdx.x - 1];
    int i = blockIdx.x * 256 + t;
    if (i < n) {
        int d = cursor[i];            // deg
        int v2 = off[i] + base;
        off[i] = v2;
        cursor[i] = v2;
        for (int p = v2; p < v2 + d; ++p) edst[p] = (unsigned short)i;
    }
    if (i == 0) off[n] = total;
}

// fill CSR; record pos[e] = CSR position of edge e (coalesced by e)
__global__ __launch_bounds__(256) void fill_kernel(const int* __restrict__ src,
                                                   const int* __restrict__ dst,
                                                   int* __restrict__ cursor,
                                                   int* __restrict__ col,
                                                   int* __restrict__ pos, int n) {
    int e = blockIdx.x * 256 + threadIdx.x;
    if (e < n) {
        int p = atomicAdd(&cursor[dst[e]], 1);
        col[p] = src[e];
        pos[e] = p;
    }
}

// ---------------- pack one f32 KxN matrix into bf16 MFMA B-fragments --------------
__device__ inline void pack_one(const float* B, int K, int N, short* out, int t) {
    int l = t & 63;
    int fs = t >> 6;
    int KS = K >> 5;
    int ct = fs / KS, ks = fs - ct * KS;
    int coln = ct * 16 + (l & 15);
    int k0 = ks * 32 + (l >> 4) * 8;
    bf16x8 v;
#pragma unroll
    for (int j = 0; j < 8; ++j)
        v[j] = f2bf(B[(size_t)(k0 + j) * N + coln]);
    *(bf16x8*)(out + (size_t)t * 8) = v;
}

__global__ __launch_bounds__(256) void pack_all_kernel(
    const float* __restrict__ Wl0, const float* __restrict__ Wr0,
    const float* __restrict__ Wl1, const float* __restrict__ Wr1,
    const float* __restrict__ Wl2, const float* __restrict__ Wr2,
    const float* __restrict__ Wf1,
    short* W0lp, short* W0rp, short* W1lp, short* W1rp,
    short* W2lp, short* W2rp, short* Wfp) {
    int t = blockIdx.x * 256 + threadIdx.x;
    if (t < 2048)              pack_one(Wl0, 128, 128, W0lp, t);
    else if (t < 4096)         pack_one(Wr0, 128, 128, W0rp, t - 2048);
    else if (t < 6144)         pack_one(Wl1, 128, 128, W1lp, t - 4096);
    else if (t < 8192)         pack_one(Wr1, 128, 128, W1rp, t - 6144);
    else if (t < 9216)         pack_one(Wl2, 128, 64,  W2lp, t - 8192);
    else if (t < 10240)        pack_one(Wr2, 128, 64,  W2rp, t - 9216);
    else if (t < 12288)        pack_one(Wf1, 128, 128, Wfp,  t - 10240);
}

// ---------------- transform GEMM: g = h@Wl ; r = h@Wr + b  (K=128) ----------------
template <int NT, bool SRC_F32, bool G_FP8>
__global__ __launch_bounds__(256) void gemm_tf_kernel(
    const void* hsrc, const short* __restrict__ Wlp, const short* __restrict__ Wrp,
    const float* __restrict__ b, void* g, short* r, int n) {
    int wave = (blockIdx.x * 256 + threadIdx.x) >> 6;
    int lane = threadIdx.x & 63;
    int rowbase = wave * 32;
    if (rowbase >= n) return;
    int gq = lane >> 4, c = lane & 15;

    bf16x8 afrag[2][4];
#pragma unroll
    for (int s = 0; s < 2; ++s) {
        int i = rowbase + s * 16 + c;
        if (i >= n) i = n - 1;
        if (SRC_F32) {
            const float* xr = (const float*)hsrc + (size_t)i * 128;
#pragma unroll
            for (int ks = 0; ks < 4; ++ks) {
                const float* p = xr + ks * 32 + gq * 8;
                float4 v0 = *(const float4*)p;
                float4 v1 = *(const float4*)(p + 4);
                bf16x8 a;
                a[0] = f2bf(v0.x); a[1] = f2bf(v0.y); a[2] = f2bf(v0.z); a[3] = f2bf(v0.w);
                a[4] = f2bf(v1.x); a[5] = f2bf(v1.y); a[6] = f2bf(v1.z); a[7] = f2bf(v1.w);
                afrag[s][ks] = a;
            }
        } else {
            const short* hr = (const short*)hsrc + (size_t)i * 128;
#pragma unroll
            for (int ks = 0; ks < 4; ++ks)
                afrag[s][ks] = *(const bf16x8*)(hr + ks * 32 + gq * 8);
        }
    }

    f32x4 acc[2][NT];
    f32x4 z = {0.f, 0.f, 0.f, 0.f};
    const int NG = NT * 16;

    // ---- phase 1: g = h @ Wl ----
#pragma unroll
    for (int s = 0; s < 2; ++s)
#pragma unroll
        for (int ct = 0; ct < NT; ++ct) acc[s][ct] = z;
#pragma unroll
    for (int ct = 0; ct < NT; ++ct)
#pragma unroll
        for (int ks = 0; ks < 4; ++ks) {
            bf16x8 bfv = *(const bf16x8*)(Wlp + ((size_t)(ct * 4 + ks) * 64 + lane) * 8);
            acc[0][ct] = __builtin_amdgcn_mfma_f32_16x16x32_bf16(afrag[0][ks], bfv, acc[0][ct], 0, 0, 0);
            acc[1][ct] = __builtin_amdgcn_mfma_f32_16x16x32_bf16(afrag[1][ks], bfv, acc[1][ct], 0, 0, 0);
        }
#pragma unroll
    for (int s = 0; s < 2; ++s)
#pragma unroll
        for (int ct = 0; ct < NT; ++ct)
#pragma unroll
            for (int rr = 0; rr < 4; ++rr) {
                int row = rowbase + s * 16 + gq * 4 + rr;
                if (row < n) {
                    float v = acc[s][ct][rr];
                    if (G_FP8) {
                        unsigned pk = __builtin_amdgcn_cvt_pk_fp8_f32(v, v, 0u, false);
                        ((unsigned char*)g)[(size_t)row * NG + ct * 16 + c] = (unsigned char)pk;
                    } else {
                        ((short*)g)[(size_t)row * NG + ct * 16 + c] = f2bf(v);
                    }
                }
            }

    // ---- phase 2: r = h @ Wr + b ----
#pragma unroll
    for (int s = 0; s < 2; ++s)
#pragma unroll
        for (int ct = 0; ct < NT; ++ct) acc[s][ct] = z;
#pragma unroll
    for (int ct = 0; ct < NT; ++ct)
#pragma unroll
        for (int ks = 0; ks < 4; ++ks) {
            bf16x8 bfv = *(const bf16x8*)(Wrp + ((size_t)(ct * 4 + ks) * 64 + lane) * 8);
            acc[0][ct] = __builtin_amdgcn_mfma_f32_16x16x32_bf16(afrag[0][ks], bfv, acc[0][ct], 0, 0, 0);
            acc[1][ct] = __builtin_amdgcn_mfma_f32_16x16x32_bf16(afrag[1][ks], bfv, acc[1][ct], 0, 0, 0);
        }
#pragma unroll
    for (int s = 0; s < 2; ++s)
#pragma unroll
        for (int ct = 0; ct < NT; ++ct)
#pragma unroll
            for (int rr = 0; rr < 4; ++rr) {
                int row = rowbase + s * 16 + gq * 4 + rr;
                if (row < n)
                    r[(size_t)row * 128 + ct * 16 + c] = f2bf(acc[s][ct][rr] + b[ct * 16 + c]);
            }
}

// ---------------- combine (fp8 g): h' = relu(mean_gather(g8) + r) ----------------
// 8 lanes/node, uint4 (16B) per lane: one instruction = full 128-B row x 8 nodes.
__device__ inline void acc_fp8x16(unsigned x, unsigned y, unsigned z, unsigned w, float* a) {
    f32x2 d;
    d = __builtin_amdgcn_cvt_pk_f32_fp8((int)x, false); a[0] += d.x;  a[1] += d.y;
    d = __builtin_amdgcn_cvt_pk_f32_fp8((int)x, true);  a[2] += d.x;  a[3] += d.y;
    d = __builtin_amdgcn_cvt_pk_f32_fp8((int)y, false); a[4] += d.x;  a[5] += d.y;
    d = __builtin_amdgcn_cvt_pk_f32_fp8((int)y, true);  a[6] += d.x;  a[7] += d.y;
    d = __builtin_amdgcn_cvt_pk_f32_fp8((int)z, false); a[8] += d.x;  a[9] += d.y;
    d = __builtin_amdgcn_cvt_pk_f32_fp8((int)z, true);  a[10] += d.x; a[11] += d.y;
    d = __builtin_amdgcn_cvt_pk_f32_fp8((int)w, false); a[12] += d.x; a[13] += d.y;
    d = __builtin_amdgcn_cvt_pk_f32_fp8((int)w, true);  a[14] += d.x; a[15] += d.y;
}

__global__ __launch_bounds__(256) void combine_fp8_kernel(
    const unsigned char* __restrict__ g8, const short* rr,
    const int* __restrict__ off, const int* __restrict__ col,
    short* outb, int n) {
    int t = blockIdx.x * 256 + threadIdx.x;
    int node = t >> 3, q = t & 7;
    if (node >= n) return;
    int qo = q * 16;                 // byte offset within 128-B row
    int p0 = off[node], p1 = off[node + 1];
    float a[16];
#pragma unroll
    for (int k = 0; k < 16; ++k) a[k] = 0.f;
    int p = p0;
    for (; p + 3 < p1; p += 4) {
        uint4 u0 = *(const uint4*)(g8 + (size_t)col[p] * 128 + qo);
        uint4 u1 = *(const uint4*)(g8 + (size_t)col[p + 1] * 128 + qo);
        uint4 u2 = *(const uint4*)(g8 + (size_t)col[p + 2] * 128 + qo);
        uint4 u3 = *(const uint4*)(g8 + (size_t)col[p + 3] * 128 + qo);
        acc_fp8x16(u0.x, u0.y, u0.z, u0.w, a);
        acc_fp8x16(u1.x, u1.y, u1.z, u1.w, a);
        acc_fp8x16(u2.x, u2.y, u2.z, u2.w, a);
        acc_fp8x16(u3.x, u3.y, u3.z, u3.w, a);
    }
    for (; p < p1; ++p) {
        uint4 u = *(const uint4*)(g8 + (size_t)col[p] * 128 + qo);
        acc_fp8x16(u.x, u.y, u.z, u.w, a);
    }
    int deg = p1 - p0;
    float inv = 1.f / (float)(deg > 1 ? deg : 1);
    const short* rrow = rr + (size_t)node * 128 + q * 16;
    bf16x8 rv0 = *(const bf16x8*)rrow;
    bf16x8 rv1 = *(const bf16x8*)(rrow + 8);
    bf16x8 o0, o1;
#pragma unroll
    for (int k = 0; k < 8; ++k) {
        o0[k] = f2bf(fmaxf(a[k] * inv + bf2f(rv0[k]), 0.f));
        o1[k] = f2bf(fmaxf(a[k + 8] * inv + bf2f(rv1[k]), 0.f));
    }
    short* orow = outb + (size_t)node * 128 + q * 16;
    *(bf16x8*)orow = o0;
    *(bf16x8*)(orow + 8) = o1;
}

// ------- combine layer 2 + fused classifier: ne = mean_gather(g) + r ; sc = ne@Wc+bc -
__global__ __launch_bounds__(256) void combine_l2_kernel(
    const short* __restrict__ g, const short* rr,
    const int* __restrict__ off, const int* __restrict__ col,
    short* neb, float* nef, const float* __restrict__ Wc,
    const float* __restrict__ bc, float* __restrict__ sc, int n) {
    int t = blockIdx.x * 256 + threadIdx.x;
    int node = t >> 3, q = t & 7;
    if (node >= n) return;
    int qo = q * 8;
    int p0 = off[node], p1 = off[node + 1];
    float a[8];
#pragma unroll
    for (int k = 0; k < 8; ++k) a[k] = 0.f;
    int p = p0;
    for (; p + 3 < p1; p += 4) {
        bf16x8 u0 = *(const bf16x8*)(g + (size_t)col[p] * 64 + qo);
        bf16x8 u1 = *(const bf16x8*)(g + (size_t)col[p + 1] * 64 + qo);
        bf16x8 u2 = *(const bf16x8*)(g + (size_t)col[p + 2] * 64 + qo);
        bf16x8 u3 = *(const bf16x8*)(g + (size_t)col[p + 3] * 64 + qo);
#pragma unroll
        for (int k = 0; k < 8; ++k)
            a[k] += (bf2f(u0[k]) + bf2f(u1[k])) + (bf2f(u2[k]) + bf2f(u3[k]));
    }
    for (; p < p1; ++p) {
        bf16x8 u0 = *(const bf16x8*)(g + (size_t)col[p] * 64 + qo);
#pragma unroll
        for (int k = 0; k < 8; ++k) a[k] += bf2f(u0[k]);
    }
    int deg = p1 - p0;
    float inv = 1.f / (float)(deg > 1 ? deg : 1);
    bf16x8 rv = *(const bf16x8*)(rr + (size_t)node * 128 + qo);
    float val[8];
#pragma unroll
    for (int k = 0; k < 8; ++k) val[k] = a[k] * inv + bf2f(rv[k]);
    float4 f0, f1;
    f0.x = val[0]; f0.y = val[1]; f0.z = val[2]; f0.w = val[3];
    f1.x = val[4]; f1.y = val[5]; f1.z = val[6]; f1.w = val[7];
    *(float4*)(nef + (size_t)node * 64 + qo) = f0;
    *(float4*)(nef + (size_t)node * 64 + qo + 4) = f1;
    bf16x8 o;
#pragma unroll
    for (int k = 0; k < 8; ++k) o[k] = f2bf(val[k]);
    *(bf16x8*)(neb + (size_t)node * 64 + qo) = o;

    float part[4];
#pragma unroll
    for (int cidx = 0; cidx < 4; ++cidx) {
        float s0 = 0.f;
#pragma unroll
        for (int k = 0; k < 8; ++k)
            s0 = fmaf(val[k], Wc[(qo + k) * 4 + cidx], s0);
        s0 += __shfl_xor(s0, 1);
        s0 += __shfl_xor(s0, 2);
        s0 += __shfl_xor(s0, 4);
        part[cidx] = s0;
    }
    if (q == 0) {
        float4 o4;
        o4.x = part[0] + bc[0]; o4.y = part[1] + bc[1];
        o4.z = part[2] + bc[2]; o4.w = part[3] + bc[3];
        *(float4*)(sc + (size_t)node * 4) = o4;
    }
}

// ------- edge MLP phase A (dst-grouped CSR order, coalesced position output) -------
__global__ __launch_bounds__(256) void edge_mlp_sorted_kernel(
    const short* __restrict__ neb, const int* __restrict__ col,
    const unsigned short* __restrict__ edst,
    const short* __restrict__ Wp, const float* __restrict__ bf1,
    const float* __restrict__ Wf2, const float* __restrict__ bf2,
    float* __restrict__ cfs, int nE) {
    int wave = (blockIdx.x * 256 + threadIdx.x) >> 6;
    int lane = threadIdx.x & 63;
    int rowbase = wave * 32;
    if (rowbase >= nE) return;
    int g = lane >> 4, c = lane & 15;

    bf16x8 afrag[2][4];
#pragma unroll
    for (int s = 0; s < 2; ++s) {
        int p = rowbase + s * 16 + c;
        const short* rs = neb + (size_t)col[p] * 64;
        const short* rd = neb + (size_t)edst[p] * 64;
        afrag[s][0] = *(const bf16x8*)(rs + g * 8);
        afrag[s][1] = *(const bf16x8*)(rs + 32 + g * 8);
        afrag[s][2] = *(const bf16x8*)(rd + g * 8);
        afrag[s][3] = *(const bf16x8*)(rd + 32 + g * 8);
    }

    f32x4 acc[2][8];
    f32x4 z = {0.f, 0.f, 0.f, 0.f};
#pragma unroll
    for (int s = 0; s < 2; ++s)
#pragma unroll
        for (int ct = 0; ct < 8; ++ct) acc[s][ct] = z;

#pragma unroll
    for (int ct = 0; ct < 8; ++ct)
#pragma unroll
        for (int ks = 0; ks < 4; ++ks) {
            bf16x8 bfv = *(const bf16x8*)(Wp + ((size_t)(ct * 4 + ks) * 64 + lane) * 8);
            acc[0][ct] = __builtin_amdgcn_mfma_f32_16x16x32_bf16(afrag[0][ks], bfv, acc[0][ct], 0, 0, 0);
            acc[1][ct] = __builtin_amdgcn_mfma_f32_16x16x32_bf16(afrag[1][ks], bfv, acc[1][ct], 0, 0, 0);
        }

    float bf1v[8], wf2v[8];
#pragma unroll
    for (int ct = 0; ct < 8; ++ct) {
        bf1v[ct] = bf1[ct * 16 + c];
        wf2v[ct] = Wf2[ct * 16 + c];
    }
    float bias2 = bf2[0];
#pragma unroll
    for (int s = 0; s < 2; ++s)
#pragma unroll
        for (int r = 0; r < 4; ++r) {
            float part = 0.f;
#pragma unroll
            for (int ct = 0; ct < 8; ++ct) {
                float hv = acc[s][ct][r] + bf1v[ct];
                hv = fmaxf(hv, 0.f);
                part = fmaf(hv, wf2v[ct], part);
            }
#pragma unroll
            for (int o = 1; o < 16; o <<= 1)
                part += __shfl_xor(part, o);
            if (c == 0) {
                int row = rowbase + s * 16 + g * 4 + r;
                cfs[row] = part + bias2;
            }
        }
}

// phase B: cf[e] = cfs[pos[e]]
__global__ __launch_bounds__(256) void permute_kernel(const float* __restrict__ cfs,
                                                      const int* __restrict__ pos,
                                                      float* __restrict__ cf, int n) {
    int e = blockIdx.x * 256 + threadIdx.x;
    if (e < n) cf[e] = cfs[pos[e]];
}

extern "C" void kernel_launch(void* const* d_in, const int* in_sizes, int n_in,
                              void* d_out, int out_size, void* d_ws, size_t ws_size,
                              hipStream_t stream) {
    const float* x   = (const float*)d_in[0];
    const int*   ei  = (const int*)d_in[1];
    const int*   src = ei;
    const int*   dst = ei + NE;
    const float* Wl0 = (const float*)d_in[2];
    const float* Wr0 = (const float*)d_in[3];
    const float* b0  = (const float*)d_in[4];
    const float* Wl1 = (const float*)d_in[5];
    const float* Wr1 = (const float*)d_in[6];
    const float* b1  = (const float*)d_in[7];
    const float* Wl2 = (const float*)d_in[8];
    const float* Wr2 = (const float*)d_in[9];
    const float* b2  = (const float*)d_in[10];
    const float* Wf1 = (const float*)d_in[11];
    const float* bf1 = (const float*)d_in[12];
    const float* Wf2 = (const float*)d_in[13];
    const float* bf2 = (const float*)d_in[14];
    const float* Wc  = (const float*)d_in[15];
    const float* bc  = (const float*)d_in[16];

    // ---- workspace carve-up (~34.2 MB; ws_size >= 37.75 MB proven in R5/R9/R10) ----
    short* sp = (short*)d_ws;
    short* W0lp = sp; sp += 128 * 128;
    short* W0rp = sp; sp += 128 * 128;
    short* W1lp = sp; sp += 128 * 128;
    short* W1rp = sp; sp += 128 * 128;
    short* W2lp = sp; sp += 128 * 64;
    short* W2rp = sp; sp += 128 * 64;
    short* Wfp  = sp; sp += 128 * 128;
    short* gb   = sp; sp += (size_t)NN * 64;    // 6.4 MB: fp8 g[NN,128]B | bf16 g2[NN,64] | cfs
    short* hb   = sp; sp += (size_t)NN * 128;   // 12.8 MB: r/h rows (in place)
    short* neb  = sp; sp += (size_t)NN * 64;    // 6.4 MB: compact bf16 node embeddings
    int* ip = (int*)sp;
    int* off    = ip; ip += 50008;
    int* cursor = ip; ip += 50000;               // also deg
    int* col    = ip; ip += 800000;
    int* bsum   = ip; ip += 256;
    int* pos    = ip; ip += NE;                  // 3.2 MB
    unsigned short* edst = (unsigned short*)ip;  // 1.6 MB

    float* cfs = (float*)gb;                     // aliases gb (free after combine_l2)

    float* ne = (float*)d_out;               // [NN,64]
    float* cf = ne + (size_t)NN * 64;        // [NE]
    float* sc = cf + NE;                     // [NN,4]

    int* deg = cursor;
    const int NB = (NN + 255) / 256;

    // --- CSR build (5 dispatches) ---
    hipMemsetAsync(deg, 0, NN * sizeof(int), stream);
    count_deg_kernel<<<(NE + 255) / 256, 256, 0, stream>>>(dst, deg, NE);
    scan1_kernel<<<NB, 256, 0, stream>>>(deg, off, bsum, NN);
    scan3x_kernel<<<NB, 256, 0, stream>>>(off, bsum, cursor, edst, NN, NE, NB);
    fill_kernel<<<(NE + 255) / 256, 256, 0, stream>>>(src, dst, cursor, col, pos, NE);

    // --- weight packs ---
    pack_all_kernel<<<48, 256, 0, stream>>>(Wl0, Wr0, Wl1, Wr1, Wl2, Wr2, Wf1,
                                            W0lp, W0rp, W1lp, W1rp, W2lp, W2rp, Wfp);

    int sgrid  = ((NN + 31) / 32 + 3) / 4;       // 391
    int cgridf = (NN * 8 + 255) / 256;           // 1563 (8 lanes/node)
    int cgrid2 = (NN * 8 + 255) / 256;           // 1563
    int egrid  = (NE / 32) / 4;                  // 6250

    // --- layer 0: A from f32 x; g0 fp8 -> gb; r0 -> hb; combine -> hb ---
    gemm_tf_kernel<8, true, true><<<sgrid, 256, 0, stream>>>(x, W0lp, W0rp, b0, gb, hb, NN);
    combine_fp8_kernel<<<cgridf, 256, 0, stream>>>((const unsigned char*)gb, hb, off, col, hb, NN);
    // --- layer 1 ---
    gemm_tf_kernel<8, false, true><<<sgrid, 256, 0, stream>>>(hb, W1lp, W1rp, b1, gb, hb, NN);
    combine_fp8_kernel<<<cgridf, 256, 0, stream>>>((const unsigned char*)gb, hb, off, col, hb, NN);
    // --- layer 2: g2 bf16 64-wide -> gb; r2 -> hb; combine -> ne + neb + sc (fused) ---
    gemm_tf_kernel<4, false, false><<<sgrid, 256, 0, stream>>>(hb, W2lp, W2rp, b2, gb, hb, NN);
    combine_l2_kernel<<<cgrid2, 256, 0, stream>>>(gb, hb, off, col, neb, ne, Wc, bc, sc, NN);

    // --- edge head (dst-grouped order; coalesced stage + permute) ---
    edge_mlp_sorted_kernel<<<egrid, 256, 0, stream>>>(neb, col, edst, Wfp, bf1, Wf2, bf2, cfs, NE);
    permute_kernel<<<(NE + 255) / 256, 256, 0, stream>>>(cfs, pos, cf, NE);
}